// Round 1
// baseline (1469.929 us; speedup 1.0000x reference)
//
#include <hip/hip_runtime.h>

// LocEncoder: PointNetConv-like fused edge-MLP + segment-max + relu.
//
// reference:
//   msg  = [x[src] (13), pos[src]-pos[dst] (3)]          [E,16]
//   h1   = relu(msg @ W1 + b1)                           [E,64]
//   h2   = h1 @ W2 + b2                                  [E,64]
//   out  = relu(segment_max(h2, dst, N))                 [N,64]
//
// relu(segment_max(.)) == max(0, max_e h2): zero-init out, atomicMax only
// positive values via signed-int bit trick (positive floats are monotone
// as signed ints; 0-bits == 0.0f).

#define N_NODES 100000
#define N_EDGES 1600000
#define D_IN 13
#define HIDDEN 64

__global__ __launch_bounds__(256) void locenc_edge_kernel(
    const float* __restrict__ x,     // [N,13]
    const float* __restrict__ pos,   // [N,3]
    const float* __restrict__ W1,    // [16,64]
    const float* __restrict__ b1,    // [64]
    const float* __restrict__ W2,    // [64,64]
    const float* __restrict__ b2,    // [64]
    const int*   __restrict__ ei,    // [2,E]
    int*         __restrict__ out)   // [N,64] as float bits
{
    const int lane  = threadIdx.x & 63;
    const int wid   = (blockIdx.x * (blockDim.x >> 6)) + (threadIdx.x >> 6);
    const int nwave = gridDim.x * (blockDim.x >> 6);

    // Per-lane weight columns in registers (lane d owns output dim d).
    float w1c[16];
#pragma unroll
    for (int k = 0; k < 16; ++k) w1c[k] = W1[k * 64 + lane];
    const float b1c = b1[lane];

    float w2c[64];
#pragma unroll
    for (int k = 0; k < 64; ++k) w2c[k] = W2[k * 64 + lane];
    const float b2c = b2[lane];

    for (int e = wid; e < N_EDGES; e += nwave) {
        const int src = ei[e];            // edge_index[0][e]
        const int dst = ei[N_EDGES + e];  // edge_index[1][e]

        // lanes 0..12: x[src][lane]; lanes 13..15: pos[src]-pos[dst]
        float m = 0.0f;
        if (lane < D_IN) {
            m = x[src * D_IN + lane];
        } else if (lane < 16) {
            const int c = lane - D_IN;
            m = pos[src * 3 + c] - pos[dst * 3 + c];
        }

        // h1[d] = relu(b1[d] + sum_k msg[k] * W1[k][d])
        float acc = b1c;
#pragma unroll
        for (int k = 0; k < 16; ++k)
            acc = fmaf(__shfl(m, k), w1c[k], acc);
        const float h1 = fmaxf(acc, 0.0f);

        // h2[d] = b2[d] + sum_k h1[k] * W2[k][d]
        float acc2 = b2c;
#pragma unroll
        for (int k = 0; k < 64; ++k)
            acc2 = fmaf(__shfl(h1, k), w2c[k], acc2);

        // relu(max(...)) with 0-init: only positive values can matter.
        if (acc2 > 0.0f) {
            atomicMax(&out[dst * 64 + lane], __float_as_int(acc2));
        }
    }
}

extern "C" void kernel_launch(void* const* d_in, const int* in_sizes, int n_in,
                              void* d_out, int out_size, void* d_ws, size_t ws_size,
                              hipStream_t stream) {
    const float* x   = (const float*)d_in[0];
    const float* pos = (const float*)d_in[1];
    const float* W1  = (const float*)d_in[2];
    const float* b1  = (const float*)d_in[3];
    const float* W2  = (const float*)d_in[4];
    const float* b2  = (const float*)d_in[5];
    const int*   ei  = (const int*)d_in[6];

    // out re-poisoned to 0xAA before every timed launch -> must zero it.
    hipMemsetAsync(d_out, 0, (size_t)out_size * sizeof(float), stream);

    const int blocks = 2048;  // 8192 waves, ~195 edges/wave
    locenc_edge_kernel<<<blocks, 256, 0, stream>>>(
        x, pos, W1, b1, W2, b2, ei, (int*)d_out);
}

// Round 2
// 412.048 us; speedup vs baseline: 3.5674x; 3.5674x over previous
//
#include <hip/hip_runtime.h>

// LocEncoder fused: per-16-edge-tile MFMA pipeline.
//   msg[16x16] @ W1[16x64] -> relu -> @ W2[64x64] -> atomicMax(out[dst])
// relu(segment_max) == max(0, max_e h2): zero-init out, atomic-smax only
// positive values (positive float bits are monotone as signed ints).
//
// GEMM2's K order is permuted (k' = n*4 + t, h1 dim = n + 16t) so the
// C-layout->A-layout transform is vectorized (ds_write_b64/ds_read_b128);
// W2's rows are permuted identically when building B-fragments, which
// leaves the dot product invariant.

#define N_NODES 100000
#define N_EDGES 1600000
#define NTILES  (N_EDGES / 16)
#define WPB 4  // waves per block

typedef short short8  __attribute__((ext_vector_type(8)));
typedef short short4v __attribute__((ext_vector_type(4)));
typedef float float4v __attribute__((ext_vector_type(4)));

__device__ inline short f2bf(float f) {  // fp32 -> bf16, round-nearest-even
    union { float f; unsigned u; } v; v.f = f;
    unsigned u = v.u;
    u += 0x7fffu + ((u >> 16) & 1u);
    return (short)(u >> 16);
}

__global__ __launch_bounds__(256) void locenc_mfma_kernel(
    const float* __restrict__ x,     // [N,13]
    const float* __restrict__ pos,   // [N,3]
    const float* __restrict__ W1,    // [16,64]
    const float* __restrict__ b1,    // [64]
    const float* __restrict__ W2,    // [64,64]
    const float* __restrict__ b2,    // [64]
    const int*   __restrict__ ei,    // [2,E]
    int*         __restrict__ out)   // [N,64] float bits
{
    // per-wave h1 tile: 16 rows x 64 bf16, row stride 72 shorts (144 B,
    // padded so ds_read_b128 lands 2-way-per-bank = free)
    __shared__ alignas(16) short h1s[WPB][16 * 72];

    const int lane = threadIdx.x & 63;
    const int wv   = threadIdx.x >> 6;
    const int q    = lane >> 4;   // quad
    const int n    = lane & 15;   // col within 16-wide slab / edge for loads

    // ---- preload W fragments (amortized over ~12 tiles/wave) ----
    // GEMM1 B-frags: B[k = q*8+j][n + 16t], K padded 16->32 with zeros.
    short8 w1f[4];
    for (int t = 0; t < 4; ++t)
        for (int j = 0; j < 8; ++j) {
            int k = q * 8 + j;
            w1f[t][j] = (k < 16) ? f2bf(W1[k * 64 + (n + 16 * t)]) : (short)0;
        }
    // GEMM2 B-frags with permuted K: k' = s*32 + q*8 + j, orig k = (k'>>2) + 16*(k'&3)
    short8 w2f[2][4];
    for (int s = 0; s < 2; ++s)
        for (int t = 0; t < 4; ++t)
            for (int j = 0; j < 8; ++j) {
                int kk = s * 32 + q * 8 + j;
                int ko = (kk >> 2) + 16 * (kk & 3);
                w2f[s][t][j] = f2bf(W2[ko * 64 + (n + 16 * t)]);
            }
    float b1c[4], b2c[4];
    for (int t = 0; t < 4; ++t) { b1c[t] = b1[n + 16 * t]; b2c[t] = b2[n + 16 * t]; }

    short* myLds = &h1s[wv][0];
    const int waveId = blockIdx.x * WPB + wv;
    const int nwave  = gridDim.x * WPB;

    for (int tt = waveId; tt < NTILES; tt += nwave) {
        const int e0  = tt * 16;
        const int src = ei[e0 + n];             // edge n of tile
        const int dst = ei[N_EDGES + e0 + n];

        // A1 frag: A[m = lane&15 = edge][k = q*8+j = msg dim], dims 16..31 zero
        short8 a1 = {0, 0, 0, 0, 0, 0, 0, 0};
        if (q == 0) {
#pragma unroll
            for (int j = 0; j < 8; ++j) a1[j] = f2bf(x[src * 13 + j]);
        } else if (q == 1) {
#pragma unroll
            for (int j = 0; j < 5; ++j) a1[j] = f2bf(x[src * 13 + 8 + j]);
#pragma unroll
            for (int c = 0; c < 3; ++c)
                a1[5 + c] = f2bf(pos[src * 3 + c] - pos[dst * 3 + c]);
        }

        // GEMM1: h1 C-frags (row = edge q*4+r, col = n + 16t)
        float4v c1[4];
#pragma unroll
        for (int t = 0; t < 4; ++t)
            c1[t] = __builtin_amdgcn_mfma_f32_16x16x32_bf16(
                a1, w1f[t], (float4v){0.f, 0.f, 0.f, 0.f}, 0, 0, 0);

        // bias + relu + bf16, LDS at k' = n*4 + t (4 consecutive shorts -> b64)
#pragma unroll
        for (int r = 0; r < 4; ++r) {
            short4v pk;
#pragma unroll
            for (int t = 0; t < 4; ++t)
                pk[t] = f2bf(fmaxf(c1[t][r] + b1c[t], 0.f));
            const int m = q * 4 + r;
            *(short4v*)(myLds + m * 72 + n * 4) = pk;
        }

        // GEMM2 A-frags: A[m = lane&15][k' = s*32 + q*8 + j]  (same-wave data,
        // compiler inserts the lgkmcnt wait; no barrier needed)
        short8 a2s0 = *(short8*)(myLds + n * 72 + q * 8);
        short8 a2s1 = *(short8*)(myLds + n * 72 + 32 + q * 8);

        float4v c2[4];
#pragma unroll
        for (int t = 0; t < 4; ++t) {
            c2[t] = __builtin_amdgcn_mfma_f32_16x16x32_bf16(
                a2s0, w2f[0][t], (float4v){0.f, 0.f, 0.f, 0.f}, 0, 0, 0);
            c2[t] = __builtin_amdgcn_mfma_f32_16x16x32_bf16(
                a2s1, w2f[1][t], c2[t], 0, 0, 0);
        }

        // epilogue: bias, positive-only atomic smax into out[dst]
#pragma unroll
        for (int r = 0; r < 4; ++r) {
            const int dr = __shfl(dst, q * 4 + r);  // dst of edge q*4+r
#pragma unroll
            for (int t = 0; t < 4; ++t) {
                float v = c2[t][r] + b2c[t];
                if (v > 0.f)
                    atomicMax(&out[dr * 64 + n + 16 * t], __float_as_int(v));
            }
        }
    }
}

extern "C" void kernel_launch(void* const* d_in, const int* in_sizes, int n_in,
                              void* d_out, int out_size, void* d_ws, size_t ws_size,
                              hipStream_t stream) {
    const float* x   = (const float*)d_in[0];
    const float* pos = (const float*)d_in[1];
    const float* W1  = (const float*)d_in[2];
    const float* b1  = (const float*)d_in[3];
    const float* W2  = (const float*)d_in[4];
    const float* b2  = (const float*)d_in[5];
    const int*   ei  = (const int*)d_in[6];

    hipMemsetAsync(d_out, 0, (size_t)out_size * sizeof(float), stream);

    const int blocks = 2048;  // 8192 waves, ~12 tiles each
    locenc_mfma_kernel<<<blocks, 256, 0, stream>>>(
        x, pos, W1, b1, W2, b2, ei, (int*)d_out);
}